// Round 1
// baseline (215.040 us; speedup 1.0000x reference)
//
#include <hip/hip_runtime.h>
#include <hip/hip_bf16.h>
#include <math.h>

#define NEG_SLOPE 0.01f

__device__ __forceinline__ float lrelu(float v) {
    return v > 0.0f ? v : NEG_SLOPE * v;
}

// ---------------------------------------------------------------------------
// Transpose W1 [k=128][j=128] -> w1t [j=128][k=128] so per-node inner loops
// read W1T rows at wave-uniform, contiguous addresses (scalar-load friendly).
// ---------------------------------------------------------------------------
__global__ void k_transpose(const float* __restrict__ W1, float* __restrict__ w1t) {
    int t = blockIdx.x * blockDim.x + threadIdx.x; // 0..16383
    int j = t >> 7, k = t & 127;
    w1t[j * 128 + k] = W1[k * 128 + j];
}

// ---------------------------------------------------------------------------
// Per-node attention logit: s[n] = dot(lrelu(X[n,:] @ W1 + b1), W2) + b2
// Thread-per-node. X row lives in 128 VGPRs (all indices compile-time).
// w1t/b1/W2 accesses are wave-uniform -> scalar loads.
// ---------------------------------------------------------------------------
__global__ void __launch_bounds__(256) k_node_score(
    const float* __restrict__ X, const float* __restrict__ w1t,
    const float* __restrict__ b1, const float* __restrict__ W2,
    const float* __restrict__ b2, float* __restrict__ sarr, int N) {
    int n = blockIdx.x * blockDim.x + threadIdx.x;
    if (n >= N) return;
    float4 x4[32];
    const float4* X4 = (const float4*)(X + (size_t)n * 128);
#pragma unroll
    for (int i = 0; i < 32; ++i) x4[i] = X4[i];

    float s = 0.0f;
    for (int j = 0; j < 128; ++j) {
        const float* wr = w1t + j * 128;  // uniform address
        float a0 = 0.f, a1 = 0.f, a2 = 0.f, a3 = 0.f;
#pragma unroll
        for (int k4 = 0; k4 < 32; ++k4) {
            float4 xv = x4[k4];
            a0 += xv.x * wr[4 * k4 + 0];
            a1 += xv.y * wr[4 * k4 + 1];
            a2 += xv.z * wr[4 * k4 + 2];
            a3 += xv.w * wr[4 * k4 + 3];
        }
        float h = (a0 + a1) + (a2 + a3) + b1[j];
        s += lrelu(h) * W2[j];
    }
    sarr[n] = s + b2[0];
}

// ---------------------------------------------------------------------------
// Per-edge member-range offsets from sorted edge_ids. off has E+1 entries:
// off[e] = first member index with edge_ids >= e. Handles empty edges.
// ---------------------------------------------------------------------------
__global__ void k_edge_offsets(const int* __restrict__ edge_ids,
                               int* __restrict__ off, int M, int E) {
    int m = blockIdx.x * blockDim.x + threadIdx.x;
    if (m >= M) return;
    int e = edge_ids[m];
    if (m == 0) {
        for (int q = 0; q <= e; ++q) off[q] = 0;
    } else {
        int p = edge_ids[m - 1];
        for (int q = p + 1; q <= e; ++q) off[q] = m;
    }
    if (m == M - 1) {
        for (int q = e + 1; q <= E; ++q) off[q] = M;
    }
}

// ---------------------------------------------------------------------------
// One wave per edge: segment softmax over member logits, weighted gather-sum
// of X rows, fused leaky_relu + tanh epilogue. Writes beta and tanh(lrelu(Z)).
// ---------------------------------------------------------------------------
__global__ void __launch_bounds__(64) k_edge_softmax_agg(
    const float* __restrict__ X, const float* __restrict__ sarr,
    const int* __restrict__ node_idx, const int* __restrict__ off,
    float* __restrict__ outZ, float* __restrict__ outBeta) {
    int e = blockIdx.x;
    int lane = threadIdx.x;
    int s0 = off[e], s1 = off[e + 1];
    int n = s1 - s0;

    __shared__ float bs[64];
    __shared__ int ns[64];

    // phase 1: segment max of logits
    float wmax = -INFINITY;
    for (int i = lane; i < n; i += 64)
        wmax = fmaxf(wmax, sarr[node_idx[s0 + i]]);
#pragma unroll
    for (int d = 1; d < 64; d <<= 1)
        wmax = fmaxf(wmax, __shfl_xor(wmax, d, 64));

    // phase 2: segment sum of exp
    float sum = 0.0f;
    for (int i = lane; i < n; i += 64)
        sum += expf(sarr[node_idx[s0 + i]] - wmax);
#pragma unroll
    for (int d = 1; d < 64; d <<= 1)
        sum += __shfl_xor(sum, d, 64);
    float inv = (n > 0) ? 1.0f / sum : 0.0f;

    // phase 3: beta + weighted row accumulation (lane owns dims 2l, 2l+1)
    float az = 0.0f, aw = 0.0f;
    const float2* X2 = (const float2*)X;
    for (int base = 0; base < n; base += 64) {
        int cnt = min(64, n - base);
        if (lane < cnt) {
            int idx = node_idx[s0 + base + lane];
            float b = expf(sarr[idx] - wmax) * inv;
            outBeta[s0 + base + lane] = b;
            bs[lane] = b;
            ns[lane] = idx;
        }
        __syncthreads();
        for (int t = 0; t < cnt; ++t) {
            float b = bs[t];
            float2 xv = X2[(size_t)ns[t] * 64 + lane];
            az += b * xv.x;
            aw += b * xv.y;
        }
        __syncthreads();
    }

    outZ[(size_t)e * 128 + 2 * lane]     = tanhf(lrelu(az));
    outZ[(size_t)e * 128 + 2 * lane + 1] = tanhf(lrelu(aw));
}

extern "C" void kernel_launch(void* const* d_in, const int* in_sizes, int n_in,
                              void* d_out, int out_size, void* d_ws, size_t ws_size,
                              hipStream_t stream) {
    const float* X  = (const float*)d_in[0];
    const float* W1 = (const float*)d_in[1];
    const float* b1 = (const float*)d_in[2];
    const float* W2 = (const float*)d_in[3];
    const float* b2 = (const float*)d_in[4];
    const int* node_idx = (const int*)d_in[5];
    const int* edge_ids = (const int*)d_in[6];

    int N = in_sizes[0] / 128;          // 100000 nodes
    int M = in_sizes[5];                // 640000 memberships
    int E = (out_size - M) / 128;       // 20000 hyperedges

    // workspace layout: w1t [128*128] | sarr [N] | off [E+1] (ints)
    float* w1t  = (float*)d_ws;
    float* sarr = w1t + 128 * 128;
    int*   off  = (int*)(sarr + N);

    float* outZ    = (float*)d_out;
    float* outBeta = outZ + (size_t)E * 128;

    k_transpose<<<64, 256, 0, stream>>>(W1, w1t);
    k_node_score<<<(N + 255) / 256, 256, 0, stream>>>(X, w1t, b1, W2, b2, sarr, N);
    k_edge_offsets<<<(M + 255) / 256, 256, 0, stream>>>(edge_ids, off, M, E);
    k_edge_softmax_agg<<<E, 64, 0, stream>>>(X, sarr, node_idx, off, outZ, outBeta);
}